// Round 2
// baseline (1135.403 us; speedup 1.0000x reference)
//
#include <hip/hip_runtime.h>
#include <math.h>

#define Tn 128
#define Hn 128
#define Wn 128
#define Cn 32
#define NVOX (Tn*Hn*Wn)   // 2097152

typedef float4 f4;

// ---- bf16 pack/unpack (RNE) ----
__device__ __forceinline__ unsigned bfpack2(float a, float b) {
  unsigned ua = __float_as_uint(a), ub = __float_as_uint(b);
  ua = (ua + 0x7FFFu + ((ua >> 16) & 1u)) >> 16;
  ub = (ub + 0x7FFFu + ((ub >> 16) & 1u)) >> 16;
  return ua | (ub << 16);
}
__device__ __forceinline__ float bflo(unsigned p) { return __uint_as_float(p << 16); }
__device__ __forceinline__ float bfhi(unsigned p) { return __uint_as_float(p & 0xFFFF0000u); }

// ---------------------------------------------------------------------------
// convM: 1->32 conv, M [T,H,W] -> Mh [T,H,W,32] channels-last bf16.
// Tile (4,4,16) = 256 voxels, 256 threads.
// ---------------------------------------------------------------------------
__global__ __launch_bounds__(256) void k_convM(
    const float* __restrict__ M, const float* __restrict__ wM,
    uint4* __restrict__ Mh)
{
  __shared__ float sm[648];                       // 6*6*18
  const int w0 = blockIdx.x*16, h0 = blockIdx.y*4, t0 = blockIdx.z*4;
  const int tid = threadIdx.x;
  for (int idx = tid; idx < 648; idx += 256) {
    int lw = idx % 18, lh = (idx/18) % 6, ld = idx/108;
    int gw = w0 - 1 + lw, gh = h0 - 1 + lh, gt = t0 - 1 + ld;
    float v = 0.f;
    if ((unsigned)gw < Wn && (unsigned)gh < Hn && (unsigned)gt < Tn)
      v = M[(gt*Hn + gh)*Wn + gw];
    sm[idx] = v;
  }
  __syncthreads();
  const int tw = tid & 15, th = (tid>>4)&3, td = tid>>6;
  float m[27];
  #pragma unroll
  for (int kd = 0; kd < 3; ++kd)
    #pragma unroll
    for (int kh = 0; kh < 3; ++kh)
      #pragma unroll
      for (int kw = 0; kw < 3; ++kw)
        m[(kd*3+kh)*3+kw] = sm[((td+kd)*6 + (th+kh))*18 + tw+kw];
  float r[32];
  #pragma unroll
  for (int c = 0; c < 32; ++c) {
    float acc = 0.f;
    #pragma unroll
    for (int k = 0; k < 27; ++k) acc += wM[c*27+k]*m[k];   // uniform -> s_load
    r[c] = acc;
  }
  const long vox = ((long)(t0+td)*Hn + (h0+th))*Wn + (w0+tw);
  uint4* dst = Mh + vox*4;
  #pragma unroll
  for (int j = 0; j < 4; ++j) {
    uint4 o;
    o.x = bfpack2(r[8*j+0], r[8*j+1]);
    o.y = bfpack2(r[8*j+2], r[8*j+3]);
    o.z = bfpack2(r[8*j+4], r[8*j+5]);
    o.w = bfpack2(r[8*j+6], r[8*j+7]);
    dst[j] = o;
  }
}

// ---------------------------------------------------------------------------
// conv0+conv1 fused: 32->1 x2 on bf16 Mh. bg2=(1-relu(conv0+b))^2; c1m=1-conv1
// Tile (4,4,8)=128 outputs, 128 threads. LDS fp32 46KB, XOR-swizzled groups.
// ---------------------------------------------------------------------------
__global__ __launch_bounds__(128) void k_conv01(
    const uint4* __restrict__ Mh, const float* __restrict__ w0p,
    const float* __restrict__ b0p, const float* __restrict__ w1p,
    float* __restrict__ bg2, float* __restrict__ c1m)
{
  __shared__ f4 s4[2880];                         // 360 cells * 8 groups fp32
  const int w0 = blockIdx.x*8, h0 = blockIdx.y*4, t0 = blockIdx.z*4;
  const int tid = threadIdx.x;
  for (int idx = tid; idx < 1440; idx += 128) {   // 360 cells * 4 uint4-chunks
    int cell = idx >> 2, j = idx & 3;
    int lw = cell % 10, lh = (cell/10) % 6, ld = cell/60;
    int gw = w0 - 1 + lw, gh = h0 - 1 + lh, gt = t0 - 1 + ld;
    uint4 v = {0u,0u,0u,0u};
    if ((unsigned)gw < Wn && (unsigned)gh < Hn && (unsigned)gt < Tn)
      v = Mh[(((long)gt*Hn+gh)*Wn+gw)*4 + j];
    f4 lo; lo.x = bflo(v.x); lo.y = bfhi(v.x); lo.z = bflo(v.y); lo.w = bfhi(v.y);
    f4 hi; hi.x = bflo(v.z); hi.y = bfhi(v.z); hi.z = bflo(v.w); hi.w = bfhi(v.w);
    s4[cell*8 + ((2*j  ) ^ (cell & 7))] = lo;
    s4[cell*8 + ((2*j+1) ^ (cell & 7))] = hi;
  }
  __syncthreads();
  const int lw = tid & 7, lh = (tid>>3)&3, ld = tid>>5;
  float acc0 = 0.f, acc1 = 0.f;
  for (int kd = 0; kd < 3; ++kd)
  for (int kh = 0; kh < 3; ++kh) {
    int cellbase = ((ld+kd)*6 + (lh+kh))*10 + lw;
    #pragma unroll
    for (int kw = 0; kw < 3; ++kw) {
      int cell = cellbase + kw;
      int koff = kd*9 + kh*3 + kw;
      #pragma unroll
      for (int g = 0; g < 8; ++g) {
        f4 mv = s4[cell*8 + (g ^ (cell & 7))];
        int cb = g*4;
        acc0 += w0p[(cb+0)*27+koff]*mv.x + w0p[(cb+1)*27+koff]*mv.y
              + w0p[(cb+2)*27+koff]*mv.z + w0p[(cb+3)*27+koff]*mv.w;
        acc1 += w1p[(cb+0)*27+koff]*mv.x + w1p[(cb+1)*27+koff]*mv.y
              + w1p[(cb+2)*27+koff]*mv.z + w1p[(cb+3)*27+koff]*mv.w;
      }
    }
  }
  const long vox = ((long)(t0+ld)*Hn + (h0+lh))*Wn + (w0+lw);
  float bg = 1.f - fmaxf(acc0 + b0p[0], 0.f);
  bg2[vox] = bg*bg;
  c1m[vox] = 1.f - acc1;
}

// ---------------------------------------------------------------------------
// gradU: grad_U[h*128+w] = sum_t bg2*(X - Usrc[t*128+h]*Vsrc[w])*Vsrc[t]
// (raw .view semantics: low-rank term inside loop is U[t*128+h]*V[w])
// ---------------------------------------------------------------------------
__global__ __launch_bounds__(512) void k_gradU(
    const float* __restrict__ X, const float* __restrict__ bg2,
    const float* __restrict__ Usrc, const float* __restrict__ Vsrc,
    float* __restrict__ Udst, const float* __restrict__ ulearn, int it)
{
  __shared__ float Vs[128], Ucol[128], red[512];
  const int h = blockIdx.x;
  const int tid = threadIdx.x;
  const int w = tid & 127, tq = tid >> 7;
  if (tid < 128) Vs[tid] = Vsrc[tid];
  else if (tid < 256) Ucol[tid-128] = Usrc[(tid-128)*128 + h];
  __syncthreads();
  const float vw = Vs[w];
  float acc = 0.f;
  const int tstart = tq*32;
  for (int t = tstart; t < tstart+32; ++t) {
    int idx = (t*Hn + h)*Wn + w;
    acc += bg2[idx]*(X[idx] - Ucol[t]*vw)*Vs[t];
  }
  red[tid] = acc;
  __syncthreads();
  if (tq == 0) {
    float s = red[w] + red[128+w] + red[256+w] + red[384+w];
    int ui = h*128 + w;
    Udst[ui] = Usrc[ui] + 1e-5f*ulearn[it]*s;
  }
}

// ---------------------------------------------------------------------------
// gradV: grad_V[t] = sum_{h,w} bg2*(X - Usrc[t*128+h]*Vsrc[w]) * Udst[h*128+w]
// uses UPDATED U (= Udst)
// ---------------------------------------------------------------------------
__global__ __launch_bounds__(256) void k_gradV(
    const float* __restrict__ X, const float* __restrict__ bg2,
    const float* __restrict__ Usrc, const float* __restrict__ Vsrc,
    const float* __restrict__ Udst, float* __restrict__ Vdst,
    const float* __restrict__ vlearn, int it)
{
  __shared__ float Uc[128], Vs[128], red[256];
  const int t = blockIdx.x, tid = threadIdx.x;
  if (tid < 128) { Uc[tid] = Usrc[t*128 + tid]; Vs[tid] = Vsrc[tid]; }
  __syncthreads();
  float acc = 0.f;
  for (int idx = tid; idx < 16384; idx += 256) {
    int h = idx >> 7, w = idx & 127;
    int gi = t*16384 + idx;
    float temp = bg2[gi]*(X[gi] - Uc[h]*Vs[w]);
    acc += temp * Udst[idx];
  }
  red[tid] = acc;
  __syncthreads();
  for (int s = 128; s > 0; s >>= 1) {
    if (tid < s) red[tid] += red[tid+s];
    __syncthreads();
  }
  if (tid == 0) Vdst[t] = Vsrc[t] + 1e-5f*vlearn[it]*red[0];
}

// ---------------------------------------------------------------------------
// q = (1 - conv1(Mh)) * (X - L)^2 with L[t,h,w] = U[h*128+w]*V[t] (final UV)
// ---------------------------------------------------------------------------
__global__ __launch_bounds__(256) void k_q(
    const float* __restrict__ X, const float* __restrict__ c1m,
    const float* __restrict__ Uf, const float* __restrict__ Vf,
    float* __restrict__ q)
{
  int idx4 = blockIdx.x*256 + threadIdx.x;        // < NVOX/4
  int vox = idx4*4;
  f4 x  = ((const f4*)X)[idx4];
  f4 cm = ((const f4*)c1m)[idx4];
  f4 u  = ((const f4*)Uf)[(vox & 16383) >> 2];
  float vt = Vf[vox >> 14];
  float d0 = x.x - u.x*vt, d1 = x.y - u.y*vt, d2 = x.z - u.z*vt, d3 = x.w - u.w*vt;
  f4 r; r.x = cm.x*d0*d0; r.y = cm.y*d1*d1; r.z = cm.z*d2*d2; r.w = cm.w*d3*d3;
  ((f4*)q)[idx4] = r;
}

// ---------------------------------------------------------------------------
// z (in-place on bf16 Mh): z = softthresh(Mh + tau_s*conv2(q), g[c]*g2[h]*th[w])
// ---------------------------------------------------------------------------
__global__ __launch_bounds__(256) void k_z(
    const float* __restrict__ q, const float* __restrict__ w2,
    uint4* __restrict__ Mh, const float* __restrict__ taup,
    const float* __restrict__ g, const float* __restrict__ g2,
    const float* __restrict__ th)
{
  __shared__ float sm[648];
  const int w0 = blockIdx.x*16, h0 = blockIdx.y*4, t0 = blockIdx.z*4;
  const int tid = threadIdx.x;
  for (int idx = tid; idx < 648; idx += 256) {
    int lw = idx % 18, lh = (idx/18) % 6, ld = idx/108;
    int gw = w0 - 1 + lw, gh = h0 - 1 + lh, gt = t0 - 1 + ld;
    float v = 0.f;
    if ((unsigned)gw < Wn && (unsigned)gh < Hn && (unsigned)gt < Tn)
      v = q[(gt*Hn + gh)*Wn + gw];
    sm[idx] = v;
  }
  __syncthreads();
  const float tau_s = log1pf(expf(taup[0]));      // softplus
  const int tw = tid & 15, thl = (tid>>4)&3, td = tid>>6;
  float m[27];
  #pragma unroll
  for (int kd = 0; kd < 3; ++kd)
    #pragma unroll
    for (int kh = 0; kh < 3; ++kh)
      #pragma unroll
      for (int kw = 0; kw < 3; ++kw)
        m[(kd*3+kh)*3+kw] = sm[((td+kd)*6 + (thl+kh))*18 + tw+kw];
  const int h = h0 + thl, w = w0 + tw;
  const long vox = ((long)(t0+td)*Hn + h)*Wn + w;
  const float thw = g2[h]*th[w];
  uint4* mh4 = Mh + vox*4;
  #pragma unroll
  for (int j = 0; j < 4; ++j) {
    uint4 p = mh4[j];
    float in[8] = {bflo(p.x), bfhi(p.x), bflo(p.y), bfhi(p.y),
                   bflo(p.z), bfhi(p.z), bflo(p.w), bfhi(p.w)};
    float out[8];
    #pragma unroll
    for (int e = 0; e < 8; ++e) {
      int c = 8*j + e;
      float acc = 0.f;
      #pragma unroll
      for (int k = 0; k < 27; ++k) acc += w2[c*27+k]*m[k];
      float r = in[e] + tau_s*acc;
      float thr = g[c]*thw;
      float a = fabsf(r) - thr;
      out[e] = (a > 0.f) ? copysignf(a, r) : 0.f;
    }
    uint4 o;
    o.x = bfpack2(out[0], out[1]);
    o.y = bfpack2(out[2], out[3]);
    o.z = bfpack2(out[4], out[5]);
    o.w = bfpack2(out[6], out[7]);
    mh4[j] = o;
  }
}

// ---------------------------------------------------------------------------
// conv4 (32->1) on bf16 z + sigmoid((y-0.5)*mask_scaling) -> M_out
// ---------------------------------------------------------------------------
__global__ __launch_bounds__(128) void k_conv4(
    const uint4* __restrict__ Z, const float* __restrict__ w4,
    const float* __restrict__ msp, float* __restrict__ Mout)
{
  __shared__ f4 s4[2880];
  const int w0 = blockIdx.x*8, h0 = blockIdx.y*4, t0 = blockIdx.z*4;
  const int tid = threadIdx.x;
  for (int idx = tid; idx < 1440; idx += 128) {
    int cell = idx >> 2, j = idx & 3;
    int lw = cell % 10, lh = (cell/10) % 6, ld = cell/60;
    int gw = w0 - 1 + lw, gh = h0 - 1 + lh, gt = t0 - 1 + ld;
    uint4 v = {0u,0u,0u,0u};
    if ((unsigned)gw < Wn && (unsigned)gh < Hn && (unsigned)gt < Tn)
      v = Z[(((long)gt*Hn+gh)*Wn+gw)*4 + j];
    f4 lo; lo.x = bflo(v.x); lo.y = bfhi(v.x); lo.z = bflo(v.y); lo.w = bfhi(v.y);
    f4 hi; hi.x = bflo(v.z); hi.y = bfhi(v.z); hi.z = bflo(v.w); hi.w = bfhi(v.w);
    s4[cell*8 + ((2*j  ) ^ (cell & 7))] = lo;
    s4[cell*8 + ((2*j+1) ^ (cell & 7))] = hi;
  }
  __syncthreads();
  const int lw = tid & 7, lh = (tid>>3)&3, ld = tid>>5;
  float acc = 0.f;
  for (int kd = 0; kd < 3; ++kd)
  for (int kh = 0; kh < 3; ++kh) {
    int cellbase = ((ld+kd)*6 + (lh+kh))*10 + lw;
    #pragma unroll
    for (int kw = 0; kw < 3; ++kw) {
      int cell = cellbase + kw;
      int koff = kd*9 + kh*3 + kw;
      #pragma unroll
      for (int g = 0; g < 8; ++g) {
        f4 mv = s4[cell*8 + (g ^ (cell & 7))];
        int cb = g*4;
        acc += w4[(cb+0)*27+koff]*mv.x + w4[(cb+1)*27+koff]*mv.y
             + w4[(cb+2)*27+koff]*mv.z + w4[(cb+3)*27+koff]*mv.w;
      }
    }
  }
  const long vox = ((long)(t0+ld)*Hn + (h0+lh))*Wn + (w0+lw);
  float y = (acc - 0.5f)*msp[0];
  Mout[vox] = 1.f/(1.f + expf(-y));
}

// ---------------------------------------------------------------------------
// copy X, U_final, V_final into d_out (M_out written by k_conv4 directly)
// ---------------------------------------------------------------------------
__global__ __launch_bounds__(256) void k_copyout(
    const float* __restrict__ X, const float* __restrict__ Uf,
    const float* __restrict__ Vf, float* __restrict__ out)
{
  const int NX4 = NVOX/4, NU4 = 16384/4, NV4 = 128/4;
  int i4 = blockIdx.x*256 + threadIdx.x;
  if (i4 < NX4)                 ((f4*)out)[i4] = ((const f4*)X)[i4];
  else if (i4 < NX4+NU4)        ((f4*)out)[i4] = ((const f4*)Uf)[i4-NX4];
  else if (i4 < NX4+NU4+NV4)    ((f4*)out)[i4] = ((const f4*)Vf)[i4-NX4-NU4];
}

extern "C" void kernel_launch(void* const* d_in, const int* in_sizes, int n_in,
                              void* d_out, int out_size, void* d_ws, size_t ws_size,
                              hipStream_t stream)
{
  const float* X   = (const float*)d_in[0];
  const float* U0  = (const float*)d_in[1];
  const float* V0  = (const float*)d_in[2];
  const float* M   = (const float*)d_in[3];
  const float* wM  = (const float*)d_in[4];
  const float* w0  = (const float*)d_in[5];
  const float* b0  = (const float*)d_in[6];
  const float* w1  = (const float*)d_in[7];
  const float* w2  = (const float*)d_in[8];
  const float* w4  = (const float*)d_in[9];
  const float* tau = (const float*)d_in[10];
  const float* ms  = (const float*)d_in[11];
  const float* g   = (const float*)d_in[12];
  const float* th  = (const float*)d_in[13];
  const float* g2  = (const float*)d_in[14];
  const float* ul  = (const float*)d_in[15];
  const float* vl  = (const float*)d_in[16];

  // workspace layout (bytes): Mh bf16 134.2MB | bg2 8MB (reused as q) |
  // c1m 8MB | Ua Ub Va Vb.  Total ~151.1MB.
  uint4* Mh  = (uint4*)d_ws;                       // NVOX*32 bf16 = NVOX*4 uint4
  float* fws = (float*)((char*)d_ws + (size_t)NVOX*32*2);
  float* bg2 = fws;                                // NVOX floats
  float* c1m = bg2 + NVOX;
  float* q   = bg2;                                // alias: bg2 dead after UV loop
  float* Ua  = c1m + NVOX;
  float* Ub  = Ua + 16384;
  float* Va  = Ub + 16384;
  float* Vb  = Va + 128;

  k_convM <<<dim3(8,32,32), 256, 0, stream>>>(M, wM, Mh);
  k_conv01<<<dim3(16,32,32), 128, 0, stream>>>(Mh, w0, b0, w1, bg2, c1m);

  for (int i = 0; i < 5; ++i) {
    const float* usrc = (i==0) ? U0 : ((i&1) ? Ua : Ub);
    const float* vsrc = (i==0) ? V0 : ((i&1) ? Va : Vb);
    float* udst = (i&1) ? Ub : Ua;
    float* vdst = (i&1) ? Vb : Va;
    k_gradU<<<128, 512, 0, stream>>>(X, bg2, usrc, vsrc, udst, ul, i);
    k_gradV<<<128, 256, 0, stream>>>(X, bg2, usrc, vsrc, udst, vdst, vl, i);
  }
  // after i=4: final U in Ua, final V in Va

  k_q    <<<2048, 256, 0, stream>>>(X, c1m, Ua, Va, q);
  k_z    <<<dim3(8,32,32), 256, 0, stream>>>(q, w2, Mh, tau, g, g2, th);
  k_conv4<<<dim3(16,32,32), 128, 0, stream>>>(Mh, w4, ms,
                                              (float*)d_out + NVOX + 16384 + 128);
  k_copyout<<<2065, 256, 0, stream>>>(X, Ua, Va, (float*)d_out);
}

// Round 3
// 1049.078 us; speedup vs baseline: 1.0823x; 1.0823x over previous
//
#include <hip/hip_runtime.h>
#include <math.h>

#define Tn 128
#define Hn 128
#define Wn 128
#define Cn 32
#define NVOX (Tn*Hn*Wn)   // 2097152

typedef float4 f4;
typedef __attribute__((ext_vector_type(8))) short short8;
typedef __attribute__((ext_vector_type(4))) float f32x4;

// ---- bf16 pack/unpack (RNE) ----
__device__ __forceinline__ unsigned bfpack2(float a, float b) {
  unsigned ua = __float_as_uint(a), ub = __float_as_uint(b);
  ua = (ua + 0x7FFFu + ((ua >> 16) & 1u)) >> 16;
  ub = (ub + 0x7FFFu + ((ub >> 16) & 1u)) >> 16;
  return ua | (ub << 16);
}
__device__ __forceinline__ short bf1(float a) {
  unsigned u = __float_as_uint(a);
  u = (u + 0x7FFFu + ((u >> 16) & 1u)) >> 16;
  return (short)u;
}
__device__ __forceinline__ float bflo(unsigned p) { return __uint_as_float(p << 16); }
__device__ __forceinline__ float bfhi(unsigned p) { return __uint_as_float(p & 0xFFFF0000u); }

union U4S8 { uint4 u; short8 s; };

// ---------------------------------------------------------------------------
// convM: 1->32 conv, M [T,H,W] -> Mh [T,H,W,32] channels-last bf16.
// ---------------------------------------------------------------------------
__global__ __launch_bounds__(256) void k_convM(
    const float* __restrict__ M, const float* __restrict__ wM,
    uint4* __restrict__ Mh)
{
  __shared__ float sm[648];                       // 6*6*18
  const int w0 = blockIdx.x*16, h0 = blockIdx.y*4, t0 = blockIdx.z*4;
  const int tid = threadIdx.x;
  for (int idx = tid; idx < 648; idx += 256) {
    int lw = idx % 18, lh = (idx/18) % 6, ld = idx/108;
    int gw = w0 - 1 + lw, gh = h0 - 1 + lh, gt = t0 - 1 + ld;
    float v = 0.f;
    if ((unsigned)gw < Wn && (unsigned)gh < Hn && (unsigned)gt < Tn)
      v = M[(gt*Hn + gh)*Wn + gw];
    sm[idx] = v;
  }
  __syncthreads();
  const int tw = tid & 15, th = (tid>>4)&3, td = tid>>6;
  float m[27];
  #pragma unroll
  for (int kd = 0; kd < 3; ++kd)
    #pragma unroll
    for (int kh = 0; kh < 3; ++kh)
      #pragma unroll
      for (int kw = 0; kw < 3; ++kw)
        m[(kd*3+kh)*3+kw] = sm[((td+kd)*6 + (th+kh))*18 + tw+kw];
  float r[32];
  #pragma unroll
  for (int c = 0; c < 32; ++c) {
    float acc = 0.f;
    #pragma unroll
    for (int k = 0; k < 27; ++k) acc += wM[c*27+k]*m[k];   // uniform -> s_load
    r[c] = acc;
  }
  const long vox = ((long)(t0+td)*Hn + (h0+th))*Wn + (w0+tw);
  uint4* dst = Mh + vox*4;
  #pragma unroll
  for (int j = 0; j < 4; ++j) {
    uint4 o;
    o.x = bfpack2(r[8*j+0], r[8*j+1]);
    o.y = bfpack2(r[8*j+2], r[8*j+3]);
    o.z = bfpack2(r[8*j+4], r[8*j+5]);
    o.w = bfpack2(r[8*j+6], r[8*j+7]);
    dst[j] = o;
  }
}

// ---------------------------------------------------------------------------
// conv0+conv1 fused via MFMA implicit GEMM.
// Tile per block: (t=4, h=4, w=16) outputs, 2 t-slabs per block.
// A = Mh tile (16 vox x 32 ch bf16, channels-last), B[k=ch][n]: n0=conv0,
// n1=conv1. 27 taps accumulated as 27 MFMAs (16x16x32 bf16).
// A-frag ds_read_b128 bank pattern (16m+4kg)%32 = uniform 8-phase floor.
// ---------------------------------------------------------------------------
__global__ __launch_bounds__(256) void k_conv01(
    const uint4* __restrict__ Mh, const float* __restrict__ w0p,
    const float* __restrict__ b0p, const float* __restrict__ w1p,
    float* __restrict__ bg2, float* __restrict__ c1m)
{
  __shared__ uint4 sA[2592];                      // 648 cells * 64B = 41.5 KB
  const int tid = threadIdx.x;
  const int lane = tid & 63, wv = tid >> 6;
  const int n = lane & 15, kg = lane >> 4;

  // B fragments: lane holds B[k=kg*8+j][n], j=0..7. Only n<2 nonzero.
  short8 Bf[27];
  #pragma unroll
  for (int tap = 0; tap < 27; ++tap) {
    short8 b;
    #pragma unroll
    for (int j = 0; j < 8; ++j) {
      float wval = 0.f;
      if (n == 0)      wval = w0p[(kg*8+j)*27 + tap];
      else if (n == 1) wval = w1p[(kg*8+j)*27 + tap];
      b[j] = bf1(wval);
    }
    Bf[tap] = b;
  }
  const float bias = b0p[0];

  const int w0v = blockIdx.x*16, h0 = blockIdx.y*4;
  for (int slab = 0; slab < 2; ++slab) {
    const int t0 = (blockIdx.z*2 + slab)*4;
    __syncthreads();
    for (int idx = tid; idx < 2592; idx += 256) {
      int cell = idx >> 2, j = idx & 3;
      int lw = cell % 18, lh = (cell/18) % 6, ld = cell/108;
      int gw = w0v - 1 + lw, gh = h0 - 1 + lh, gt = t0 - 1 + ld;
      uint4 v = {0u,0u,0u,0u};
      if ((unsigned)gw < Wn && (unsigned)gh < Hn && (unsigned)gt < Tn)
        v = Mh[(((long)gt*Hn+gh)*Wn+gw)*4 + j];
      sA[cell*4 + j] = v;
    }
    __syncthreads();
    const int ld = wv;                            // wave's t-row in tile
    for (int lh = 0; lh < 4; ++lh) {
      f32x4 acc = {0.f,0.f,0.f,0.f};
      #pragma unroll
      for (int kd = 0; kd < 3; ++kd)
      #pragma unroll
      for (int kh = 0; kh < 3; ++kh) {
        const int cellbase = ((ld+kd)*6 + (lh+kh))*18 + n;   // + m (=lane&15)
        #pragma unroll
        for (int kw = 0; kw < 3; ++kw) {
          U4S8 a; a.u = sA[(cellbase + kw)*4 + kg];
          acc = __builtin_amdgcn_mfma_f32_16x16x32_bf16(
                  a.s, Bf[kd*9 + kh*3 + kw], acc, 0, 0, 0);
        }
      }
      // C/D: row m = kg*4+r (voxel w), col = n
      if (n < 2) {
        const long vbase = ((long)(t0+ld)*Hn + (h0+lh))*Wn + w0v + kg*4;
        #pragma unroll
        for (int r = 0; r < 4; ++r) {
          float y = acc[r];
          if (n == 0) { float bg = 1.f - fmaxf(y + bias, 0.f); bg2[vbase+r] = bg*bg; }
          else        { c1m[vbase+r] = 1.f - y; }
        }
      }
    }
  }
}

// ---------------------------------------------------------------------------
// gradU: grad_U[h*128+w] = sum_t bg2*(X - Usrc[t*128+h]*Vsrc[w])*Vsrc[t]
// (raw .view semantics)
// ---------------------------------------------------------------------------
__global__ __launch_bounds__(512) void k_gradU(
    const float* __restrict__ X, const float* __restrict__ bg2,
    const float* __restrict__ Usrc, const float* __restrict__ Vsrc,
    float* __restrict__ Udst, const float* __restrict__ ulearn, int it)
{
  __shared__ float Vs[128], Ucol[128], red[512];
  const int h = blockIdx.x;
  const int tid = threadIdx.x;
  const int w = tid & 127, tq = tid >> 7;
  if (tid < 128) Vs[tid] = Vsrc[tid];
  else if (tid < 256) Ucol[tid-128] = Usrc[(tid-128)*128 + h];
  __syncthreads();
  const float vw = Vs[w];
  float acc = 0.f;
  const int tstart = tq*32;
  for (int t = tstart; t < tstart+32; ++t) {
    int idx = (t*Hn + h)*Wn + w;
    acc += bg2[idx]*(X[idx] - Ucol[t]*vw)*Vs[t];
  }
  red[tid] = acc;
  __syncthreads();
  if (tq == 0) {
    float s = red[w] + red[128+w] + red[256+w] + red[384+w];
    int ui = h*128 + w;
    Udst[ui] = Usrc[ui] + 1e-5f*ulearn[it]*s;
  }
}

// ---------------------------------------------------------------------------
// gradV: uses UPDATED U (= Udst)
// ---------------------------------------------------------------------------
__global__ __launch_bounds__(256) void k_gradV(
    const float* __restrict__ X, const float* __restrict__ bg2,
    const float* __restrict__ Usrc, const float* __restrict__ Vsrc,
    const float* __restrict__ Udst, float* __restrict__ Vdst,
    const float* __restrict__ vlearn, int it)
{
  __shared__ float Uc[128], Vs[128], red[256];
  const int t = blockIdx.x, tid = threadIdx.x;
  if (tid < 128) { Uc[tid] = Usrc[t*128 + tid]; Vs[tid] = Vsrc[tid]; }
  __syncthreads();
  float acc = 0.f;
  for (int idx = tid; idx < 16384; idx += 256) {
    int h = idx >> 7, w = idx & 127;
    int gi = t*16384 + idx;
    float temp = bg2[gi]*(X[gi] - Uc[h]*Vs[w]);
    acc += temp * Udst[idx];
  }
  red[tid] = acc;
  __syncthreads();
  for (int s = 128; s > 0; s >>= 1) {
    if (tid < s) red[tid] += red[tid+s];
    __syncthreads();
  }
  if (tid == 0) Vdst[t] = Vsrc[t] + 1e-5f*vlearn[it]*red[0];
}

// ---------------------------------------------------------------------------
// q = (1 - conv1(Mh)) * (X - L)^2 with L[t,h,w] = U[h*128+w]*V[t] (final UV)
// ---------------------------------------------------------------------------
__global__ __launch_bounds__(256) void k_q(
    const float* __restrict__ X, const float* __restrict__ c1m,
    const float* __restrict__ Uf, const float* __restrict__ Vf,
    float* __restrict__ q)
{
  int idx4 = blockIdx.x*256 + threadIdx.x;        // < NVOX/4
  int vox = idx4*4;
  f4 x  = ((const f4*)X)[idx4];
  f4 cm = ((const f4*)c1m)[idx4];
  f4 u  = ((const f4*)Uf)[(vox & 16383) >> 2];
  float vt = Vf[vox >> 14];
  float d0 = x.x - u.x*vt, d1 = x.y - u.y*vt, d2 = x.z - u.z*vt, d3 = x.w - u.w*vt;
  f4 r; r.x = cm.x*d0*d0; r.y = cm.y*d1*d1; r.z = cm.z*d2*d2; r.w = cm.w*d3*d3;
  ((f4*)q)[idx4] = r;
}

// ---------------------------------------------------------------------------
// z (in-place on bf16 Mh): z = softthresh(Mh + tau_s*conv2(q), g[c]*g2[h]*th[w])
// ---------------------------------------------------------------------------
__global__ __launch_bounds__(256) void k_z(
    const float* __restrict__ q, const float* __restrict__ w2,
    uint4* __restrict__ Mh, const float* __restrict__ taup,
    const float* __restrict__ g, const float* __restrict__ g2,
    const float* __restrict__ th)
{
  __shared__ float sm[648];
  const int w0 = blockIdx.x*16, h0 = blockIdx.y*4, t0 = blockIdx.z*4;
  const int tid = threadIdx.x;
  for (int idx = tid; idx < 648; idx += 256) {
    int lw = idx % 18, lh = (idx/18) % 6, ld = idx/108;
    int gw = w0 - 1 + lw, gh = h0 - 1 + lh, gt = t0 - 1 + ld;
    float v = 0.f;
    if ((unsigned)gw < Wn && (unsigned)gh < Hn && (unsigned)gt < Tn)
      v = q[(gt*Hn + gh)*Wn + gw];
    sm[idx] = v;
  }
  __syncthreads();
  const float tau_s = log1pf(expf(taup[0]));      // softplus
  const int tw = tid & 15, thl = (tid>>4)&3, td = tid>>6;
  float m[27];
  #pragma unroll
  for (int kd = 0; kd < 3; ++kd)
    #pragma unroll
    for (int kh = 0; kh < 3; ++kh)
      #pragma unroll
      for (int kw = 0; kw < 3; ++kw)
        m[(kd*3+kh)*3+kw] = sm[((td+kd)*6 + (thl+kh))*18 + tw+kw];
  const int h = h0 + thl, w = w0 + tw;
  const long vox = ((long)(t0+td)*Hn + h)*Wn + w;
  const float thw = g2[h]*th[w];
  uint4* mh4 = Mh + vox*4;
  #pragma unroll
  for (int j = 0; j < 4; ++j) {
    uint4 p = mh4[j];
    float in[8] = {bflo(p.x), bfhi(p.x), bflo(p.y), bfhi(p.y),
                   bflo(p.z), bfhi(p.z), bflo(p.w), bfhi(p.w)};
    float out[8];
    #pragma unroll
    for (int e = 0; e < 8; ++e) {
      int c = 8*j + e;
      float acc = 0.f;
      #pragma unroll
      for (int k = 0; k < 27; ++k) acc += w2[c*27+k]*m[k];
      float r = in[e] + tau_s*acc;
      float thr = g[c]*thw;
      float a = fabsf(r) - thr;
      out[e] = (a > 0.f) ? copysignf(a, r) : 0.f;
    }
    uint4 o;
    o.x = bfpack2(out[0], out[1]);
    o.y = bfpack2(out[2], out[3]);
    o.z = bfpack2(out[4], out[5]);
    o.w = bfpack2(out[6], out[7]);
    mh4[j] = o;
  }
}

// ---------------------------------------------------------------------------
// conv4 (32->1) via MFMA + sigmoid((y-0.5)*mask_scaling) -> M_out
// ---------------------------------------------------------------------------
__global__ __launch_bounds__(256) void k_conv4(
    const uint4* __restrict__ Z, const float* __restrict__ w4,
    const float* __restrict__ msp, float* __restrict__ Mout)
{
  __shared__ uint4 sA[2592];
  const int tid = threadIdx.x;
  const int lane = tid & 63, wv = tid >> 6;
  const int n = lane & 15, kg = lane >> 4;

  short8 Bf[27];
  #pragma unroll
  for (int tap = 0; tap < 27; ++tap) {
    short8 b;
    #pragma unroll
    for (int j = 0; j < 8; ++j) {
      float wval = (n == 0) ? w4[(kg*8+j)*27 + tap] : 0.f;
      b[j] = bf1(wval);
    }
    Bf[tap] = b;
  }
  const float ms = msp[0];

  const int w0v = blockIdx.x*16, h0 = blockIdx.y*4;
  for (int slab = 0; slab < 2; ++slab) {
    const int t0 = (blockIdx.z*2 + slab)*4;
    __syncthreads();
    for (int idx = tid; idx < 2592; idx += 256) {
      int cell = idx >> 2, j = idx & 3;
      int lw = cell % 18, lh = (cell/18) % 6, ld = cell/108;
      int gw = w0v - 1 + lw, gh = h0 - 1 + lh, gt = t0 - 1 + ld;
      uint4 v = {0u,0u,0u,0u};
      if ((unsigned)gw < Wn && (unsigned)gh < Hn && (unsigned)gt < Tn)
        v = Z[(((long)gt*Hn+gh)*Wn+gw)*4 + j];
      sA[cell*4 + j] = v;
    }
    __syncthreads();
    const int ld = wv;
    for (int lh = 0; lh < 4; ++lh) {
      f32x4 acc = {0.f,0.f,0.f,0.f};
      #pragma unroll
      for (int kd = 0; kd < 3; ++kd)
      #pragma unroll
      for (int kh = 0; kh < 3; ++kh) {
        const int cellbase = ((ld+kd)*6 + (lh+kh))*18 + n;
        #pragma unroll
        for (int kw = 0; kw < 3; ++kw) {
          U4S8 a; a.u = sA[(cellbase + kw)*4 + kg];
          acc = __builtin_amdgcn_mfma_f32_16x16x32_bf16(
                  a.s, Bf[kd*9 + kh*3 + kw], acc, 0, 0, 0);
        }
      }
      if (n == 0) {
        const long vbase = ((long)(t0+ld)*Hn + (h0+lh))*Wn + w0v + kg*4;
        #pragma unroll
        for (int r = 0; r < 4; ++r) {
          float y = (acc[r] - 0.5f)*ms;
          Mout[vbase+r] = 1.f/(1.f + expf(-y));
        }
      }
    }
  }
}

// ---------------------------------------------------------------------------
// copy X, U_final, V_final into d_out (M_out written by k_conv4 directly)
// ---------------------------------------------------------------------------
__global__ __launch_bounds__(256) void k_copyout(
    const float* __restrict__ X, const float* __restrict__ Uf,
    const float* __restrict__ Vf, float* __restrict__ out)
{
  const int NX4 = NVOX/4, NU4 = 16384/4, NV4 = 128/4;
  int i4 = blockIdx.x*256 + threadIdx.x;
  if (i4 < NX4)                 ((f4*)out)[i4] = ((const f4*)X)[i4];
  else if (i4 < NX4+NU4)        ((f4*)out)[i4] = ((const f4*)Uf)[i4-NX4];
  else if (i4 < NX4+NU4+NV4)    ((f4*)out)[i4] = ((const f4*)Vf)[i4-NX4-NU4];
}

extern "C" void kernel_launch(void* const* d_in, const int* in_sizes, int n_in,
                              void* d_out, int out_size, void* d_ws, size_t ws_size,
                              hipStream_t stream)
{
  const float* X   = (const float*)d_in[0];
  const float* U0  = (const float*)d_in[1];
  const float* V0  = (const float*)d_in[2];
  const float* M   = (const float*)d_in[3];
  const float* wM  = (const float*)d_in[4];
  const float* w0  = (const float*)d_in[5];
  const float* b0  = (const float*)d_in[6];
  const float* w1  = (const float*)d_in[7];
  const float* w2  = (const float*)d_in[8];
  const float* w4  = (const float*)d_in[9];
  const float* tau = (const float*)d_in[10];
  const float* ms  = (const float*)d_in[11];
  const float* g   = (const float*)d_in[12];
  const float* th  = (const float*)d_in[13];
  const float* g2  = (const float*)d_in[14];
  const float* ul  = (const float*)d_in[15];
  const float* vl  = (const float*)d_in[16];

  // workspace: Mh bf16 134.2MB | bg2 8MB (aliased by q) | c1m 8MB | U/V bufs
  uint4* Mh  = (uint4*)d_ws;                       // NVOX*32 bf16 = NVOX*4 uint4
  float* fws = (float*)((char*)d_ws + (size_t)NVOX*32*2);
  float* bg2 = fws;                                // NVOX floats
  float* c1m = bg2 + NVOX;
  float* q   = bg2;                                // alias: bg2 dead after UV loop
  float* Ua  = c1m + NVOX;
  float* Ub  = Ua + 16384;
  float* Va  = Ub + 16384;
  float* Vb  = Va + 128;

  k_convM <<<dim3(8,32,32), 256, 0, stream>>>(M, wM, Mh);
  k_conv01<<<dim3(8,32,16), 256, 0, stream>>>(Mh, w0, b0, w1, bg2, c1m);

  for (int i = 0; i < 5; ++i) {
    const float* usrc = (i==0) ? U0 : ((i&1) ? Ua : Ub);
    const float* vsrc = (i==0) ? V0 : ((i&1) ? Va : Vb);
    float* udst = (i&1) ? Ub : Ua;
    float* vdst = (i&1) ? Vb : Va;
    k_gradU<<<128, 512, 0, stream>>>(X, bg2, usrc, vsrc, udst, ul, i);
    k_gradV<<<128, 256, 0, stream>>>(X, bg2, usrc, vsrc, udst, vdst, vl, i);
  }
  // after i=4: final U in Ua, final V in Va

  k_q    <<<2048, 256, 0, stream>>>(X, c1m, Ua, Va, q);
  k_z    <<<dim3(8,32,32), 256, 0, stream>>>(q, w2, Mh, tau, g, g2, th);
  k_conv4<<<dim3(8,32,16), 256, 0, stream>>>(Mh, w4, ms,
                                             (float*)d_out + NVOX + 16384 + 128);
  k_copyout<<<2065, 256, 0, stream>>>(X, Ua, Va, (float*)d_out);
}

// Round 4
// 557.133 us; speedup vs baseline: 2.0379x; 1.8830x over previous
//
#include <hip/hip_runtime.h>
#include <math.h>

#define Tn 128
#define Hn 128
#define Wn 128
#define Cn 32
#define NVOX (Tn*Hn*Wn)   // 2097152

typedef float4 f4;
typedef __attribute__((ext_vector_type(8))) short short8;
typedef __attribute__((ext_vector_type(4))) float f32x4;

// ---- bf16 pack/unpack (RNE) ----
__device__ __forceinline__ unsigned bfpack2(float a, float b) {
  unsigned ua = __float_as_uint(a), ub = __float_as_uint(b);
  ua = (ua + 0x7FFFu + ((ua >> 16) & 1u)) >> 16;
  ub = (ub + 0x7FFFu + ((ub >> 16) & 1u)) >> 16;
  return ua | (ub << 16);
}
__device__ __forceinline__ float bflo(unsigned p) { return __uint_as_float(p << 16); }
__device__ __forceinline__ float bfhi(unsigned p) { return __uint_as_float(p & 0xFFFF0000u); }

union U4S8 { uint4 u; short8 s; };

// ---------------------------------------------------------------------------
// convM: 1->32 conv, M [T,H,W] -> Mh [T,H,W,32] channels-last bf16.
// ---------------------------------------------------------------------------
__global__ __launch_bounds__(256) void k_convM(
    const float* __restrict__ M, const float* __restrict__ wM,
    uint4* __restrict__ Mh)
{
  __shared__ float sm[648];                       // 6*6*18
  const int w0 = blockIdx.x*16, h0 = blockIdx.y*4, t0 = blockIdx.z*4;
  const int tid = threadIdx.x;
  for (int idx = tid; idx < 648; idx += 256) {
    int lw = idx % 18, lh = (idx/18) % 6, ld = idx/108;
    int gw = w0 - 1 + lw, gh = h0 - 1 + lh, gt = t0 - 1 + ld;
    float v = 0.f;
    if ((unsigned)gw < Wn && (unsigned)gh < Hn && (unsigned)gt < Tn)
      v = M[(gt*Hn + gh)*Wn + gw];
    sm[idx] = v;
  }
  __syncthreads();
  const int tw = tid & 15, th = (tid>>4)&3, td = tid>>6;
  float m[27];
  #pragma unroll
  for (int kd = 0; kd < 3; ++kd)
    #pragma unroll
    for (int kh = 0; kh < 3; ++kh)
      #pragma unroll
      for (int kw = 0; kw < 3; ++kw)
        m[(kd*3+kh)*3+kw] = sm[((td+kd)*6 + (th+kh))*18 + tw+kw];
  float r[32];
  #pragma unroll
  for (int c = 0; c < 32; ++c) {
    float acc = 0.f;
    #pragma unroll
    for (int k = 0; k < 27; ++k) acc += wM[c*27+k]*m[k];   // uniform -> s_load
    r[c] = acc;
  }
  const long vox = ((long)(t0+td)*Hn + (h0+th))*Wn + (w0+tw);
  uint4* dst = Mh + vox*4;
  #pragma unroll
  for (int j = 0; j < 4; ++j) {
    uint4 o;
    o.x = bfpack2(r[8*j+0], r[8*j+1]);
    o.y = bfpack2(r[8*j+2], r[8*j+3]);
    o.z = bfpack2(r[8*j+4], r[8*j+5]);
    o.w = bfpack2(r[8*j+6], r[8*j+7]);
    dst[j] = o;
  }
}

// ---------------------------------------------------------------------------
// conv0+conv1 fused via MFMA implicit GEMM, B-fragments in LDS.
// Tile per block: (t=4, h=4, w=16) outputs x 2 t-slabs. Wave wv owns t-row.
// kd-outer loop: 18 A-frags resident (72 VGPRs), 9 B reads/kd (LDS, mostly
// broadcast-zero for lanes n>=2), 4 independent acc chains (lh).
// ---------------------------------------------------------------------------
__global__ __launch_bounds__(256) void k_conv01(
    const uint4* __restrict__ Mh, const float* __restrict__ w0p,
    const float* __restrict__ b0p, const float* __restrict__ w1p,
    float* __restrict__ bg2, float* __restrict__ c1m)
{
  __shared__ uint4 sA[2592];                      // 648 cells * 64B = 41.5 KB
  __shared__ uint4 sB[220];                       // 27 taps*2cols*4kg + 4 zero
  const int tid = threadIdx.x;
  const int lane = tid & 63, wv = tid >> 6;
  const int n = lane & 15, kg = lane >> 4;

  // build B in LDS: sB[tap*8 + col*4 + kg] = 8 bf16 weights (ch kg*8..+7)
  for (int idx = tid; idx < 220; idx += 256) {
    uint4 v = {0u,0u,0u,0u};
    if (idx < 216) {
      int tap = idx >> 3, col = (idx >> 2) & 1, kgi = idx & 3;
      const float* wp = col ? w1p : w0p;
      v.x = bfpack2(wp[(kgi*8+0)*27+tap], wp[(kgi*8+1)*27+tap]);
      v.y = bfpack2(wp[(kgi*8+2)*27+tap], wp[(kgi*8+3)*27+tap]);
      v.z = bfpack2(wp[(kgi*8+4)*27+tap], wp[(kgi*8+5)*27+tap]);
      v.w = bfpack2(wp[(kgi*8+6)*27+tap], wp[(kgi*8+7)*27+tap]);
    }
    sB[idx] = v;
  }
  const float bias = b0p[0];
  // per-lane B address: taps advance by bstep; zero block for n>=2
  const int bbase = (n < 2) ? (n*4 + kg) : (216 + kg);
  const int bstep = (n < 2) ? 8 : 0;

  const int w0v = blockIdx.x*16, h0 = blockIdx.y*4;
  for (int slab = 0; slab < 2; ++slab) {
    const int t0 = (blockIdx.z*2 + slab)*4;
    __syncthreads();
    for (int idx = tid; idx < 2592; idx += 256) {
      int cell = idx >> 2, j = idx & 3;
      int lw = cell % 18, lh = (cell/18) % 6, ld = cell/108;
      int gw = w0v - 1 + lw, gh = h0 - 1 + lh, gt = t0 - 1 + ld;
      uint4 v = {0u,0u,0u,0u};
      if ((unsigned)gw < Wn && (unsigned)gh < Hn && (unsigned)gt < Tn)
        v = Mh[(((long)gt*Hn+gh)*Wn+gw)*4 + j];
      sA[cell*4 + j] = v;
    }
    __syncthreads();

    const int ld = wv;                            // wave's t-row in tile
    f32x4 acc[4];
    #pragma unroll
    for (int i = 0; i < 4; ++i) acc[i] = (f32x4){0.f,0.f,0.f,0.f};

    #pragma unroll
    for (int kd = 0; kd < 3; ++kd) {
      U4S8 A[6][3];                               // 18 frags = 72 VGPRs
      #pragma unroll
      for (int hr = 0; hr < 6; ++hr)
        #pragma unroll
        for (int kw = 0; kw < 3; ++kw)
          A[hr][kw].u = sA[(((ld+kd)*6 + hr)*18 + n + kw)*4 + kg];
      #pragma unroll
      for (int kh = 0; kh < 3; ++kh)
        #pragma unroll
        for (int kw = 0; kw < 3; ++kw) {
          const int tap = kd*9 + kh*3 + kw;
          U4S8 b; b.u = sB[tap*bstep + bbase];
          #pragma unroll
          for (int lh = 0; lh < 4; ++lh)
            acc[lh] = __builtin_amdgcn_mfma_f32_16x16x32_bf16(
                        A[lh+kh][kw].s, b.s, acc[lh], 0, 0, 0);
        }
    }
    // C/D: row m = kg*4+r (voxel w), col = n
    if (n < 2) {
      #pragma unroll
      for (int lh = 0; lh < 4; ++lh) {
        const long vbase = ((long)(t0+ld)*Hn + (h0+lh))*Wn + w0v + kg*4;
        #pragma unroll
        for (int r = 0; r < 4; ++r) {
          float y = acc[lh][r];
          if (n == 0) { float bg = 1.f - fmaxf(y + bias, 0.f); bg2[vbase+r] = bg*bg; }
          else        { c1m[vbase+r] = 1.f - y; }
        }
      }
    }
  }
}

// ---------------------------------------------------------------------------
// gradU: grad_U[h*128+w] = sum_t bg2*(X - Usrc[t*128+h]*Vsrc[w])*Vsrc[t]
// (raw .view semantics)
// ---------------------------------------------------------------------------
__global__ __launch_bounds__(512) void k_gradU(
    const float* __restrict__ X, const float* __restrict__ bg2,
    const float* __restrict__ Usrc, const float* __restrict__ Vsrc,
    float* __restrict__ Udst, const float* __restrict__ ulearn, int it)
{
  __shared__ float Vs[128], Ucol[128], red[512];
  const int h = blockIdx.x;
  const int tid = threadIdx.x;
  const int w = tid & 127, tq = tid >> 7;
  if (tid < 128) Vs[tid] = Vsrc[tid];
  else if (tid < 256) Ucol[tid-128] = Usrc[(tid-128)*128 + h];
  __syncthreads();
  const float vw = Vs[w];
  float acc = 0.f;
  const int tstart = tq*32;
  for (int t = tstart; t < tstart+32; ++t) {
    int idx = (t*Hn + h)*Wn + w;
    acc += bg2[idx]*(X[idx] - Ucol[t]*vw)*Vs[t];
  }
  red[tid] = acc;
  __syncthreads();
  if (tq == 0) {
    float s = red[w] + red[128+w] + red[256+w] + red[384+w];
    int ui = h*128 + w;
    Udst[ui] = Usrc[ui] + 1e-5f*ulearn[it]*s;
  }
}

// ---------------------------------------------------------------------------
// gradV: uses UPDATED U (= Udst)
// ---------------------------------------------------------------------------
__global__ __launch_bounds__(256) void k_gradV(
    const float* __restrict__ X, const float* __restrict__ bg2,
    const float* __restrict__ Usrc, const float* __restrict__ Vsrc,
    const float* __restrict__ Udst, float* __restrict__ Vdst,
    const float* __restrict__ vlearn, int it)
{
  __shared__ float Uc[128], Vs[128], red[256];
  const int t = blockIdx.x, tid = threadIdx.x;
  if (tid < 128) { Uc[tid] = Usrc[t*128 + tid]; Vs[tid] = Vsrc[tid]; }
  __syncthreads();
  float acc = 0.f;
  for (int idx = tid; idx < 16384; idx += 256) {
    int h = idx >> 7, w = idx & 127;
    int gi = t*16384 + idx;
    float temp = bg2[gi]*(X[gi] - Uc[h]*Vs[w]);
    acc += temp * Udst[idx];
  }
  red[tid] = acc;
  __syncthreads();
  for (int s = 128; s > 0; s >>= 1) {
    if (tid < s) red[tid] += red[tid+s];
    __syncthreads();
  }
  if (tid == 0) Vdst[t] = Vsrc[t] + 1e-5f*vlearn[it]*red[0];
}

// ---------------------------------------------------------------------------
// q = (1 - conv1(Mh)) * (X - L)^2 with L[t,h,w] = U[h*128+w]*V[t] (final UV)
// ---------------------------------------------------------------------------
__global__ __launch_bounds__(256) void k_q(
    const float* __restrict__ X, const float* __restrict__ c1m,
    const float* __restrict__ Uf, const float* __restrict__ Vf,
    float* __restrict__ q)
{
  int idx4 = blockIdx.x*256 + threadIdx.x;        // < NVOX/4
  int vox = idx4*4;
  f4 x  = ((const f4*)X)[idx4];
  f4 cm = ((const f4*)c1m)[idx4];
  f4 u  = ((const f4*)Uf)[(vox & 16383) >> 2];
  float vt = Vf[vox >> 14];
  float d0 = x.x - u.x*vt, d1 = x.y - u.y*vt, d2 = x.z - u.z*vt, d3 = x.w - u.w*vt;
  f4 r; r.x = cm.x*d0*d0; r.y = cm.y*d1*d1; r.z = cm.z*d2*d2; r.w = cm.w*d3*d3;
  ((f4*)q)[idx4] = r;
}

// ---------------------------------------------------------------------------
// z (in-place on bf16 Mh): z = softthresh(Mh + tau_s*conv2(q), g[c]*g2[h]*th[w])
// ---------------------------------------------------------------------------
__global__ __launch_bounds__(256) void k_z(
    const float* __restrict__ q, const float* __restrict__ w2,
    uint4* __restrict__ Mh, const float* __restrict__ taup,
    const float* __restrict__ g, const float* __restrict__ g2,
    const float* __restrict__ th)
{
  __shared__ float sm[648];
  const int w0 = blockIdx.x*16, h0 = blockIdx.y*4, t0 = blockIdx.z*4;
  const int tid = threadIdx.x;
  for (int idx = tid; idx < 648; idx += 256) {
    int lw = idx % 18, lh = (idx/18) % 6, ld = idx/108;
    int gw = w0 - 1 + lw, gh = h0 - 1 + lh, gt = t0 - 1 + ld;
    float v = 0.f;
    if ((unsigned)gw < Wn && (unsigned)gh < Hn && (unsigned)gt < Tn)
      v = q[(gt*Hn + gh)*Wn + gw];
    sm[idx] = v;
  }
  __syncthreads();
  const float tau_s = log1pf(expf(taup[0]));      // softplus
  const int tw = tid & 15, thl = (tid>>4)&3, td = tid>>6;
  float m[27];
  #pragma unroll
  for (int kd = 0; kd < 3; ++kd)
    #pragma unroll
    for (int kh = 0; kh < 3; ++kh)
      #pragma unroll
      for (int kw = 0; kw < 3; ++kw)
        m[(kd*3+kh)*3+kw] = sm[((td+kd)*6 + (thl+kh))*18 + tw+kw];
  const int h = h0 + thl, w = w0 + tw;
  const long vox = ((long)(t0+td)*Hn + h)*Wn + w;
  const float thw = g2[h]*th[w];
  uint4* mh4 = Mh + vox*4;
  #pragma unroll
  for (int j = 0; j < 4; ++j) {
    uint4 p = mh4[j];
    float in[8] = {bflo(p.x), bfhi(p.x), bflo(p.y), bfhi(p.y),
                   bflo(p.z), bfhi(p.z), bflo(p.w), bfhi(p.w)};
    float out[8];
    #pragma unroll
    for (int e = 0; e < 8; ++e) {
      int c = 8*j + e;
      float acc = 0.f;
      #pragma unroll
      for (int k = 0; k < 27; ++k) acc += w2[c*27+k]*m[k];
      float r = in[e] + tau_s*acc;
      float thr = g[c]*thw;
      float a = fabsf(r) - thr;
      out[e] = (a > 0.f) ? copysignf(a, r) : 0.f;
    }
    uint4 o;
    o.x = bfpack2(out[0], out[1]);
    o.y = bfpack2(out[2], out[3]);
    o.z = bfpack2(out[4], out[5]);
    o.w = bfpack2(out[6], out[7]);
    mh4[j] = o;
  }
}

// ---------------------------------------------------------------------------
// conv4 (32->1) via MFMA (B in LDS) + sigmoid((y-0.5)*mask_scaling) -> M_out
// ---------------------------------------------------------------------------
__global__ __launch_bounds__(256) void k_conv4(
    const uint4* __restrict__ Z, const float* __restrict__ w4,
    const float* __restrict__ msp, float* __restrict__ Mout)
{
  __shared__ uint4 sA[2592];
  __shared__ uint4 sB[112];                       // 27 taps*4kg + 4 zero
  const int tid = threadIdx.x;
  const int lane = tid & 63, wv = tid >> 6;
  const int n = lane & 15, kg = lane >> 4;

  for (int idx = tid; idx < 112; idx += 256) {
    uint4 v = {0u,0u,0u,0u};
    if (idx < 108) {
      int tap = idx >> 2, kgi = idx & 3;
      v.x = bfpack2(w4[(kgi*8+0)*27+tap], w4[(kgi*8+1)*27+tap]);
      v.y = bfpack2(w4[(kgi*8+2)*27+tap], w4[(kgi*8+3)*27+tap]);
      v.z = bfpack2(w4[(kgi*8+4)*27+tap], w4[(kgi*8+5)*27+tap]);
      v.w = bfpack2(w4[(kgi*8+6)*27+tap], w4[(kgi*8+7)*27+tap]);
    }
    sB[idx] = v;
  }
  const float ms = msp[0];
  const int bbase = (n == 0) ? kg : (108 + kg);
  const int bstep = (n == 0) ? 4 : 0;

  const int w0v = blockIdx.x*16, h0 = blockIdx.y*4;
  for (int slab = 0; slab < 2; ++slab) {
    const int t0 = (blockIdx.z*2 + slab)*4;
    __syncthreads();
    for (int idx = tid; idx < 2592; idx += 256) {
      int cell = idx >> 2, j = idx & 3;
      int lw = cell % 18, lh = (cell/18) % 6, ld = cell/108;
      int gw = w0v - 1 + lw, gh = h0 - 1 + lh, gt = t0 - 1 + ld;
      uint4 v = {0u,0u,0u,0u};
      if ((unsigned)gw < Wn && (unsigned)gh < Hn && (unsigned)gt < Tn)
        v = Z[(((long)gt*Hn+gh)*Wn+gw)*4 + j];
      sA[cell*4 + j] = v;
    }
    __syncthreads();

    const int ld = wv;
    f32x4 acc[4];
    #pragma unroll
    for (int i = 0; i < 4; ++i) acc[i] = (f32x4){0.f,0.f,0.f,0.f};

    #pragma unroll
    for (int kd = 0; kd < 3; ++kd) {
      U4S8 A[6][3];
      #pragma unroll
      for (int hr = 0; hr < 6; ++hr)
        #pragma unroll
        for (int kw = 0; kw < 3; ++kw)
          A[hr][kw].u = sA[(((ld+kd)*6 + hr)*18 + n + kw)*4 + kg];
      #pragma unroll
      for (int kh = 0; kh < 3; ++kh)
        #pragma unroll
        for (int kw = 0; kw < 3; ++kw) {
          const int tap = kd*9 + kh*3 + kw;
          U4S8 b; b.u = sB[tap*bstep + bbase];
          #pragma unroll
          for (int lh = 0; lh < 4; ++lh)
            acc[lh] = __builtin_amdgcn_mfma_f32_16x16x32_bf16(
                        A[lh+kh][kw].s, b.s, acc[lh], 0, 0, 0);
        }
    }
    if (n == 0) {
      #pragma unroll
      for (int lh = 0; lh < 4; ++lh) {
        const long vbase = ((long)(t0+ld)*Hn + (h0+lh))*Wn + w0v + kg*4;
        #pragma unroll
        for (int r = 0; r < 4; ++r) {
          float y = (acc[lh][r] - 0.5f)*ms;
          Mout[vbase+r] = 1.f/(1.f + expf(-y));
        }
      }
    }
  }
}

// ---------------------------------------------------------------------------
// copy X, U_final, V_final into d_out (M_out written by k_conv4 directly)
// ---------------------------------------------------------------------------
__global__ __launch_bounds__(256) void k_copyout(
    const float* __restrict__ X, const float* __restrict__ Uf,
    const float* __restrict__ Vf, float* __restrict__ out)
{
  const int NX4 = NVOX/4, NU4 = 16384/4, NV4 = 128/4;
  int i4 = blockIdx.x*256 + threadIdx.x;
  if (i4 < NX4)                 ((f4*)out)[i4] = ((const f4*)X)[i4];
  else if (i4 < NX4+NU4)        ((f4*)out)[i4] = ((const f4*)Uf)[i4-NX4];
  else if (i4 < NX4+NU4+NV4)    ((f4*)out)[i4] = ((const f4*)Vf)[i4-NX4-NU4];
}

extern "C" void kernel_launch(void* const* d_in, const int* in_sizes, int n_in,
                              void* d_out, int out_size, void* d_ws, size_t ws_size,
                              hipStream_t stream)
{
  const float* X   = (const float*)d_in[0];
  const float* U0  = (const float*)d_in[1];
  const float* V0  = (const float*)d_in[2];
  const float* M   = (const float*)d_in[3];
  const float* wM  = (const float*)d_in[4];
  const float* w0  = (const float*)d_in[5];
  const float* b0  = (const float*)d_in[6];
  const float* w1  = (const float*)d_in[7];
  const float* w2  = (const float*)d_in[8];
  const float* w4  = (const float*)d_in[9];
  const float* tau = (const float*)d_in[10];
  const float* ms  = (const float*)d_in[11];
  const float* g   = (const float*)d_in[12];
  const float* th  = (const float*)d_in[13];
  const float* g2  = (const float*)d_in[14];
  const float* ul  = (const float*)d_in[15];
  const float* vl  = (const float*)d_in[16];

  // workspace: Mh bf16 134.2MB | bg2 8MB (aliased by q) | c1m 8MB | U/V bufs
  uint4* Mh  = (uint4*)d_ws;                       // NVOX*32 bf16 = NVOX*4 uint4
  float* fws = (float*)((char*)d_ws + (size_t)NVOX*32*2);
  float* bg2 = fws;                                // NVOX floats
  float* c1m = bg2 + NVOX;
  float* q   = bg2;                                // alias: bg2 dead after UV loop
  float* Ua  = c1m + NVOX;
  float* Ub  = Ua + 16384;
  float* Va  = Ub + 16384;
  float* Vb  = Va + 128;

  k_convM <<<dim3(8,32,32), 256, 0, stream>>>(M, wM, Mh);
  k_conv01<<<dim3(8,32,16), 256, 0, stream>>>(Mh, w0, b0, w1, bg2, c1m);

  for (int i = 0; i < 5; ++i) {
    const float* usrc = (i==0) ? U0 : ((i&1) ? Ua : Ub);
    const float* vsrc = (i==0) ? V0 : ((i&1) ? Va : Vb);
    float* udst = (i&1) ? Ub : Ua;
    float* vdst = (i&1) ? Vb : Va;
    k_gradU<<<128, 512, 0, stream>>>(X, bg2, usrc, vsrc, udst, ul, i);
    k_gradV<<<128, 256, 0, stream>>>(X, bg2, usrc, vsrc, udst, vdst, vl, i);
  }
  // after i=4: final U in Ua, final V in Va

  k_q    <<<2048, 256, 0, stream>>>(X, c1m, Ua, Va, q);
  k_z    <<<dim3(8,32,32), 256, 0, stream>>>(q, w2, Mh, tau, g, g2, th);
  k_conv4<<<dim3(8,32,16), 256, 0, stream>>>(Mh, w4, ms,
                                             (float*)d_out + NVOX + 16384 + 128);
  k_copyout<<<2065, 256, 0, stream>>>(X, Ua, Va, (float*)d_out);
}